// Round 13
// baseline (223.157 us; speedup 1.0000x reference)
//
#include <hip/hip_runtime.h>
#include <stdint.h>

// DkNetCL fused: megakernel (cvt + 4x conv3x3, LDS ping-pong, deferred SRePro
// -> c4[b]) + MFMA FC (double-bf16 weights, wave-private LDS-staged B) +
// finalize. Conv = implicit GEMM mfma_f32_16x16x32_bf16, M=Cout, K=Cin/tap.
// R12: net_k was latency-bound (1 blk/CU, 8 waves, MfmaUtil 32%). R13: 1024
// threads / 16 waves (4 waves/SIMD) = one row-pair per wave, same verified
// body; prep kernels + tmp-zero merged into one dispatch (6 -> 4 nodes).

typedef __bf16 bf16x8 __attribute__((ext_vector_type(8)));
typedef float f32x4 __attribute__((ext_vector_type(4)));
typedef unsigned short u16;
typedef unsigned int u32;

__device__ __forceinline__ u16 f2bf(float f) {          // fp32 -> bf16 RNE (prep)
    union { float f; u32 i; } v; v.f = f;
    u32 r = v.i + 0x7FFFu + ((v.i >> 16) & 1u);
    return (u16)(r >> 16);
}
__device__ __forceinline__ float bf2f(u16 u) {
    union { u32 i; float f; } v; v.i = ((u32)u) << 16;
    return v.f;
}
__device__ __forceinline__ u16 bfc(float f) {           // HW cvt (fast path)
    union { __bf16 h; u16 u; } x; x.h = (__bf16)f; return x.u;
}
union frag_cast { uint4 u; bf16x8 f; };

// swizzled u16 offset of 16B-chunk c (0..3) of pixel p (0..1023)
__device__ __forceinline__ int swz(int p, int c) {
    return p * 32 + ((c ^ ((p >> 1) & 3)) * 8);
}

// ---- prep_all: conv wfrag + fc double-bf16 wfrag + zero tmp, one dispatch ---
// blocks 0..255: wfc; 256..273: conv wfrag; 274: zero tmp.
__global__ void prep_all_k(const float* __restrict__ w0, const float* __restrict__ w1,
                           const float* __restrict__ w2, const float* __restrict__ w3,
                           const float* __restrict__ fcw,
                           u16* __restrict__ wfrag, u16* __restrict__ wfc,
                           float* __restrict__ tmp)
{
    int gid = blockIdx.x;
    int tid = threadIdx.x;
    if (gid < 256) {                                    // FC weights hi/lo
        int idx = gid * 256 + tid;                      // 0..65535
        int lane = idx & 63, step = idx >> 6;
        int j = lane & 15, kq = lane >> 4;
        u16 hi[8], lo[8];
#pragma unroll
        for (int e = 0; e < 8; e++) {
            int k = step * 32 + kq * 8 + e;             // NHWC k
            int c = k & 31, p = k >> 5;
            float f = (j < 10) ? fcw[j * 32768 + c * 1024 + p] : 0.f;
            u16 h = f2bf(f);
            hi[e] = h;
            lo[e] = f2bf(f - bf2f(h));
        }
        uint4 ph, pl;
        ph.x = (u32)hi[0] | ((u32)hi[1] << 16); ph.y = (u32)hi[2] | ((u32)hi[3] << 16);
        ph.z = (u32)hi[4] | ((u32)hi[5] << 16); ph.w = (u32)hi[6] | ((u32)hi[7] << 16);
        pl.x = (u32)lo[0] | ((u32)lo[1] << 16); pl.y = (u32)lo[2] | ((u32)lo[3] << 16);
        pl.z = (u32)lo[4] | ((u32)lo[5] << 16); pl.w = (u32)lo[6] | ((u32)lo[7] << 16);
        reinterpret_cast<uint4*>(wfc)[idx] = ph;
        reinterpret_cast<uint4*>(wfc)[65536 + idx] = pl;
    } else if (gid < 274) {                             // conv weights
        int idx = (gid - 256) * 256 + tid;              // 4*9*2*64 = 4608
        if (idx >= 4 * 9 * 2 * 64) return;
        int lane  = idx & 63;
        int mh    = (idx >> 6) & 1;
        int tap   = (idx >> 7) % 9;
        int layer = (idx >> 7) / 9;
        const float* w = layer == 0 ? w0 : layer == 1 ? w1 : layer == 2 ? w2 : w3;
        int cin_act = (layer == 0) ? 3 : 32;
        int cout = mh * 16 + (lane & 15);
        int cin0 = (lane >> 4) * 8;
        int dy = tap / 3, dx = tap % 3;
        u16 v[8];
        for (int j = 0; j < 8; j++) {
            int cin = cin0 + j;
            float f = (cin < cin_act) ? w[((cout * cin_act + cin) * 3 + dy) * 3 + dx] : 0.f;
            v[j] = f2bf(f);
        }
        uint4 pack;
        pack.x = (u32)v[0] | ((u32)v[1] << 16);
        pack.y = (u32)v[2] | ((u32)v[3] << 16);
        pack.z = (u32)v[4] | ((u32)v[5] << 16);
        pack.w = (u32)v[6] | ((u32)v[7] << 16);
        reinterpret_cast<uint4*>(wfrag)[idx] = pack;
    } else {                                            // zero fc partials
#pragma unroll
        for (int i = 0; i < 40; i++) tmp[i * 256 + tid] = 0.f;
    }
}

// ------------------------------ megakernel ----------------------------------
// block = 1 sample, 1024 thr (16 waves, 4/SIMD). LDS ping-pong 2 x 1024pix x
// 32ch bf16, chunk-swizzled. wave w: one output row-pair (rows 2w, 2w+1).
__global__ void __launch_bounds__(1024)
net_k(const float* __restrict__ x, const u16* __restrict__ wfrag,
      u16* __restrict__ u4, float* __restrict__ c4)
{
    __shared__ u16 lds[2][32768];
    __shared__ float red[16][4];                        // [wave][layer]
    __shared__ uint4 zslot;                             // zero B-frag for OOB
    const int b = blockIdx.x;
    const int tid = threadIdx.x;
    const int lane = tid & 63;
    const int wv = tid >> 6;                            // 0..15
    const int px = lane & 15;
    const int kq = lane >> 4;
    float vn[4];

    // ---- cvt: fp32 NCHW -> bf16 NHWC(32ch, ch3..31=0), swizzled lds[0] ----
    const float* xb = x + (size_t)b * 3072;
    if (tid == 0) zslot = make_uint4(0, 0, 0, 0);
#pragma unroll
    for (int it = 0; it < 4; it++) {
        int pix = it * 256 + wv * 16 + px;              // 16 waves x 16 pix
        int c = kq;                                     // chunk = lane>>4
        uint4 val = make_uint4(0, 0, 0, 0);
        if (c == 0) {
            float f0 = xb[pix], f1 = xb[1024 + pix], f2 = xb[2048 + pix];
            val.x = (u32)bfc(f0) | ((u32)bfc(f1) << 16);
            val.y = (u32)bfc(f2);
        }
        *reinterpret_cast<uint4*>(&lds[0][swz(pix, c)]) = val;
    }

    const int oA = wv * 2;                              // this wave's row pair
#pragma unroll 1
    for (int l = 0; l < 4; l++) {
        bf16x8 W[3][3][2];
        const uint4* wl = reinterpret_cast<const uint4*>(wfrag + l * 9216);
#pragma unroll
        for (int dy = 0; dy < 3; dy++)
#pragma unroll
            for (int dx = 0; dx < 3; dx++)
#pragma unroll
                for (int mh = 0; mh < 2; mh++) {
                    frag_cast fc;
                    fc.u = wl[((dy * 3 + dx) * 2 + mh) * 64 + lane];
                    W[dy][dx][mh] = fc.f;
                }
        const u16* src = lds[l & 1];
        u16* dst = lds[(l & 1) ^ 1];
        f32x4 vacc = (f32x4)0.f;
        __syncthreads();                                // prev writes visible

        f32x4 accA[2][2]; f32x4 accB[2][2];             // [mhalf][ntile]
#pragma unroll
        for (int mh = 0; mh < 2; mh++)
#pragma unroll
            for (int nt = 0; nt < 2; nt++) { accA[mh][nt] = (f32x4)0.f; accB[mh][nt] = (f32x4)0.f; }

#pragma unroll
        for (int k = 0; k < 4; k++) {
            int ri = oA - 1 + k;                        // input row
            if (ri >= 0 && ri < 32) {
                bf16x8 bfr[2][3];                       // [ntile][dx]
#pragma unroll
                for (int nt = 0; nt < 2; nt++)
#pragma unroll
                    for (int d = 0; d < 3; d++) {
                        int xx = nt * 16 + px + d - 1;
                        bool oob = ((unsigned)xx >= 32u);
                        int xs = oob ? (nt * 16 + px) : xx;
                        const uint4* pr = oob ? &zslot
                            : reinterpret_cast<const uint4*>(&src[swz(ri * 32 + xs, kq)]);
                        frag_cast fc;
                        fc.u = *pr;
                        bfr[nt][d] = fc.f;
                    }
                if (k <= 2) {
#pragma unroll
                    for (int mh = 0; mh < 2; mh++)
#pragma unroll
                        for (int nt = 0; nt < 2; nt++)
#pragma unroll
                            for (int d = 0; d < 3; d++)
                                accA[mh][nt] = __builtin_amdgcn_mfma_f32_16x16x32_bf16(
                                    W[k][d][mh], bfr[nt][d], accA[mh][nt], 0, 0, 0);
                }
                if (k >= 1) {
#pragma unroll
                    for (int mh = 0; mh < 2; mh++)
#pragma unroll
                        for (int nt = 0; nt < 2; nt++)
#pragma unroll
                            for (int d = 0; d < 3; d++)
                                accB[mh][nt] = __builtin_amdgcn_mfma_f32_16x16x32_bf16(
                                    W[k - 1][d][mh], bfr[nt][d], accB[mh][nt], 0, 0, 0);
                }
            }
        }
        // epilogue: D col=lane&15(px), row(ch)=(lane>>4)*4+r
#pragma unroll
        for (int mh = 0; mh < 2; mh++)
#pragma unroll
            for (int nt = 0; nt < 2; nt++) {
                int cch = mh * 2 + (kq >> 1);
                int sub = (kq & 1) * 4;
                f32x4 a = accA[mh][nt];
                vacc += a * a;
                ushort4 h = make_ushort4(bfc(a[0]), bfc(a[1]), bfc(a[2]), bfc(a[3]));
                int P0 = oA * 32 + nt * 16 + px;
                *reinterpret_cast<ushort4*>(&dst[swz(P0, cch) + sub]) = h;
                f32x4 c = accB[mh][nt];
                vacc += c * c;
                ushort4 h2 = make_ushort4(bfc(c[0]), bfc(c[1]), bfc(c[2]), bfc(c[3]));
                int P1 = (oA + 1) * 32 + nt * 16 + px;
                *reinterpret_cast<ushort4*>(&dst[swz(P1, cch) + sub]) = h2;
            }
        vn[l] = vacc[0] + vacc[1] + vacc[2] + vacc[3];
    }

    // ---- norm chain -> c4[b] ----
#pragma unroll
    for (int l = 0; l < 4; l++)
#pragma unroll
        for (int off = 32; off; off >>= 1) vn[l] += __shfl_xor(vn[l], off);
    if (lane == 0) {
#pragma unroll
        for (int l = 0; l < 4; l++) red[wv][l] = vn[l];
    }
    __syncthreads();                                    // red + final lds[0] visible
    float c = 1.f;
#pragma unroll
    for (int l = 0; l < 4; l++) {
        float n = 0.f;
#pragma unroll
        for (int w = 0; w < 16; w++) n += red[w][l];
        c = c * (2.f / (2.f + c * c * n));
    }
    if (tid == 0) c4[b] = c;

    // ---- writeback final activation (lds[0], unswizzle -> linear NHWC) ----
    u16* ub = u4 + (size_t)b * 32768;
#pragma unroll
    for (int it = 0; it < 4; it++) {
        int pix = it * 256 + wv * 16 + px;
        int cch = kq;
        *reinterpret_cast<uint4*>(ub + pix * 32 + cch * 8) =
            *reinterpret_cast<const uint4*>(&lds[0][swz(pix, cch)]);
    }
}

// --------------- FC: MFMA, M=16(j), N=16 samples, 32-way k-split ------------
// Wave-private LDS staging: 4-lane-contiguous 64B global loads (coalesced),
// swizzled LDS slots (2-way banks), T14 split (load chunk c+1 -> regs, compute
// chunk c, then write regs -> LDS). No barriers (slots are wave-private).
#define FSTG 4
__global__ void __launch_bounds__(256)
fc_mfma_k(const u16* __restrict__ u4, const u16* __restrict__ wfc,
          float* __restrict__ tmp)
{
    __shared__ uint4 sb[2][4 * FSTG * 64];              // 2 x 16KB
    const int lane = threadIdx.x & 63;
    const int wv = threadIdx.x >> 6;
    // XCD-grouped remap: the 8 blocks sharing one sample-tile -> same bid&7
    const int rb = ((blockIdx.x & 7) << 6) + (blockIdx.x >> 3);
    const int wid = rb * 4 + wv;                        // 0..2047
    const int kc = wid & 31;                            // k-chunk (1024 elems)
    const int st = wid >> 5;                            // sample tile (16)
    const int px = lane & 15, kq = lane >> 4;
    const int a = lane >> 2, p = lane & 3;              // staging: sample, piece
    const u16* gB = u4 + (size_t)(st * 16 + a) * 32768 + kc * 1024 + p * 8;
    const int wslot = wv * FSTG * 64 + a * 4 + (p ^ (a & 3));
    const int rslot = wv * FSTG * 64 + px * 4 + (kq ^ (px & 3));
    const uint4* Ah = reinterpret_cast<const uint4*>(wfc) + kc * 32 * 64 + lane;
    const uint4* Al = Ah + 65536;
    f32x4 acc = (f32x4)0.f;
    uint4 rg[FSTG];

#pragma unroll
    for (int si = 0; si < FSTG; si++)
        rg[si] = *reinterpret_cast<const uint4*>(gB + si * 32);
#pragma unroll
    for (int si = 0; si < FSTG; si++)
        sb[0][wslot + si * 64] = rg[si];

#pragma unroll 1
    for (int c2 = 0; c2 < 8; c2++) {
        if (c2 < 7) {
#pragma unroll
            for (int si = 0; si < FSTG; si++)
                rg[si] = *reinterpret_cast<const uint4*>(gB + ((c2 + 1) * FSTG + si) * 32);
        }
#pragma unroll
        for (int si = 0; si < FSTG; si++) {
            int s = c2 * FSTG + si;
            frag_cast aa, al2, bb;
            aa.u  = Ah[s * 64];
            al2.u = Al[s * 64];
            bb.u  = sb[c2 & 1][rslot + si * 64];
            acc = __builtin_amdgcn_mfma_f32_16x16x32_bf16(aa.f,  bb.f, acc, 0, 0, 0);
            acc = __builtin_amdgcn_mfma_f32_16x16x32_bf16(al2.f, bb.f, acc, 0, 0, 0);
        }
        if (c2 < 7) {
#pragma unroll
            for (int si = 0; si < FSTG; si++)
                sb[(c2 + 1) & 1][wslot + si * 64] = rg[si];
        }
    }
    int sample = st * 16 + px;                          // D col = lane&15
#pragma unroll
    for (int r = 0; r < 4; r++) {
        int j = kq * 4 + r;                             // D row
        if (j < 10) atomicAdd(&tmp[sample * 10 + j], acc[r]);
    }
}

// ------------------- finalize: out = c4[b]*tmp + bias -----------------------
__global__ void finalize_k(const float* __restrict__ tmp, const float* __restrict__ c4,
                           const float* __restrict__ fcb, float* __restrict__ out)
{
    int i = blockIdx.x * 256 + threadIdx.x;
    if (i >= 10240) return;
    int b = i / 10, j = i - b * 10;
    out[i] = c4[b] * tmp[i] + fcb[j];
}

// ------------------------------- launcher -----------------------------------
extern "C" void kernel_launch(void* const* d_in, const int* in_sizes, int n_in,
                              void* d_out, int out_size, void* d_ws, size_t ws_size,
                              hipStream_t stream)
{
    const float* x   = (const float*)d_in[0];
    const float* cw0 = (const float*)d_in[1];
    const float* cw1 = (const float*)d_in[2];
    const float* cw2 = (const float*)d_in[3];
    const float* cw3 = (const float*)d_in[4];
    const float* fcw = (const float*)d_in[5];
    const float* fcb = (const float*)d_in[6];
    float* out = (float*)d_out;
    char* ws = (char*)d_ws;

    // ws layout (~66.2 MB)
    const size_t USZ = (size_t)1024 * 32768 * 2;        // 64 MB activations
    u16* uA    = (u16*)ws;
    u16* wfrag = (u16*)(ws + USZ);                      // 73728 B (pad 81920)
    u16* wfc   = (u16*)(ws + USZ + 81920);              // 2 MB (hi+lo)
    float* tmp = (float*)(ws + USZ + 81920 + 2097152);  // 40960 B
    float* c4  = tmp + 10240;                           // 4096 B

    prep_all_k<<<275, 256, 0, stream>>>(cw0, cw1, cw2, cw3, fcw, wfrag, wfc, tmp);
    net_k<<<1024, 1024, 0, stream>>>(x, wfrag, uA, c4);
    fc_mfma_k<<<512, 256, 0, stream>>>(uA, wfc, tmp);
    finalize_k<<<40, 256, 0, stream>>>(tmp, c4, fcb, out);
}

// Round 14
// 196.633 us; speedup vs baseline: 1.1349x; 1.1349x over previous
//
#include <hip/hip_runtime.h>
#include <stdint.h>

// DkNetCL fused: megakernel (cvt + 4x conv3x3, LDS ping-pong, deferred SRePro
// -> c4[b]) + MFMA FC (double-bf16 weights, wave-private LDS-staged B) +
// finalize. Conv = implicit GEMM mfma_f32_16x16x32_bf16, M=Cout, K=Cin/tap.
// R13 post-mortem: 16 waves spilled (VGPR capped 64, hbm 2x from scratch).
// R14: rolling W window (Wc/Wp, 48 regs instead of 72) + explicit
// __launch_bounds__(1024,4) to set the 128-VGPR cap. Same math, same layout.

typedef __bf16 bf16x8 __attribute__((ext_vector_type(8)));
typedef float f32x4 __attribute__((ext_vector_type(4)));
typedef unsigned short u16;
typedef unsigned int u32;

__device__ __forceinline__ u16 f2bf(float f) {          // fp32 -> bf16 RNE (prep)
    union { float f; u32 i; } v; v.f = f;
    u32 r = v.i + 0x7FFFu + ((v.i >> 16) & 1u);
    return (u16)(r >> 16);
}
__device__ __forceinline__ float bf2f(u16 u) {
    union { u32 i; float f; } v; v.i = ((u32)u) << 16;
    return v.f;
}
__device__ __forceinline__ u16 bfc(float f) {           // HW cvt (fast path)
    union { __bf16 h; u16 u; } x; x.h = (__bf16)f; return x.u;
}
union frag_cast { uint4 u; bf16x8 f; };

// swizzled u16 offset of 16B-chunk c (0..3) of pixel p (0..1023)
__device__ __forceinline__ int swz(int p, int c) {
    return p * 32 + ((c ^ ((p >> 1) & 3)) * 8);
}

// ---- prep_all: conv wfrag + fc double-bf16 wfrag + zero tmp, one dispatch ---
// blocks 0..255: wfc; 256..273: conv wfrag; 274: zero tmp.
__global__ void prep_all_k(const float* __restrict__ w0, const float* __restrict__ w1,
                           const float* __restrict__ w2, const float* __restrict__ w3,
                           const float* __restrict__ fcw,
                           u16* __restrict__ wfrag, u16* __restrict__ wfc,
                           float* __restrict__ tmp)
{
    int gid = blockIdx.x;
    int tid = threadIdx.x;
    if (gid < 256) {                                    // FC weights hi/lo
        int idx = gid * 256 + tid;                      // 0..65535
        int lane = idx & 63, step = idx >> 6;
        int j = lane & 15, kq = lane >> 4;
        u16 hi[8], lo[8];
#pragma unroll
        for (int e = 0; e < 8; e++) {
            int k = step * 32 + kq * 8 + e;             // NHWC k
            int c = k & 31, p = k >> 5;
            float f = (j < 10) ? fcw[j * 32768 + c * 1024 + p] : 0.f;
            u16 h = f2bf(f);
            hi[e] = h;
            lo[e] = f2bf(f - bf2f(h));
        }
        uint4 ph, pl;
        ph.x = (u32)hi[0] | ((u32)hi[1] << 16); ph.y = (u32)hi[2] | ((u32)hi[3] << 16);
        ph.z = (u32)hi[4] | ((u32)hi[5] << 16); ph.w = (u32)hi[6] | ((u32)hi[7] << 16);
        pl.x = (u32)lo[0] | ((u32)lo[1] << 16); pl.y = (u32)lo[2] | ((u32)lo[3] << 16);
        pl.z = (u32)lo[4] | ((u32)lo[5] << 16); pl.w = (u32)lo[6] | ((u32)lo[7] << 16);
        reinterpret_cast<uint4*>(wfc)[idx] = ph;
        reinterpret_cast<uint4*>(wfc)[65536 + idx] = pl;
    } else if (gid < 274) {                             // conv weights
        int idx = (gid - 256) * 256 + tid;              // 4*9*2*64 = 4608
        if (idx >= 4 * 9 * 2 * 64) return;
        int lane  = idx & 63;
        int mh    = (idx >> 6) & 1;
        int tap   = (idx >> 7) % 9;
        int layer = (idx >> 7) / 9;
        const float* w = layer == 0 ? w0 : layer == 1 ? w1 : layer == 2 ? w2 : w3;
        int cin_act = (layer == 0) ? 3 : 32;
        int cout = mh * 16 + (lane & 15);
        int cin0 = (lane >> 4) * 8;
        int dy = tap / 3, dx = tap % 3;
        u16 v[8];
        for (int j = 0; j < 8; j++) {
            int cin = cin0 + j;
            float f = (cin < cin_act) ? w[((cout * cin_act + cin) * 3 + dy) * 3 + dx] : 0.f;
            v[j] = f2bf(f);
        }
        uint4 pack;
        pack.x = (u32)v[0] | ((u32)v[1] << 16);
        pack.y = (u32)v[2] | ((u32)v[3] << 16);
        pack.z = (u32)v[4] | ((u32)v[5] << 16);
        pack.w = (u32)v[6] | ((u32)v[7] << 16);
        reinterpret_cast<uint4*>(wfrag)[idx] = pack;
    } else {                                            // zero fc partials
#pragma unroll
        for (int i = 0; i < 40; i++) tmp[i * 256 + tid] = 0.f;
    }
}

// ------------------------------ megakernel ----------------------------------
// block = 1 sample, 1024 thr (16 waves, 4/SIMD, VGPR cap 128). LDS ping-pong
// 2 x 1024pix x 32ch bf16, chunk-swizzled. wave w: rows 2w, 2w+1. Rolling W:
// iter k loads dy=k row (Wc), accB uses dy=k-1 (Wp) -> 48 W regs, not 72.
__global__ void __launch_bounds__(1024, 4)
net_k(const float* __restrict__ x, const u16* __restrict__ wfrag,
      u16* __restrict__ u4, float* __restrict__ c4)
{
    __shared__ u16 lds[2][32768];
    __shared__ float red[16][4];                        // [wave][layer]
    __shared__ uint4 zslot;                             // zero B-frag for OOB
    const int b = blockIdx.x;
    const int tid = threadIdx.x;
    const int lane = tid & 63;
    const int wv = tid >> 6;                            // 0..15
    const int px = lane & 15;
    const int kq = lane >> 4;
    float vn[4];

    // ---- cvt: fp32 NCHW -> bf16 NHWC(32ch, ch3..31=0), swizzled lds[0] ----
    const float* xb = x + (size_t)b * 3072;
    if (tid == 0) zslot = make_uint4(0, 0, 0, 0);
#pragma unroll
    for (int it = 0; it < 4; it++) {
        int pix = it * 256 + wv * 16 + px;              // 16 waves x 16 pix
        int c = kq;                                     // chunk = lane>>4
        uint4 val = make_uint4(0, 0, 0, 0);
        if (c == 0) {
            float f0 = xb[pix], f1 = xb[1024 + pix], f2 = xb[2048 + pix];
            val.x = (u32)bfc(f0) | ((u32)bfc(f1) << 16);
            val.y = (u32)bfc(f2);
        }
        *reinterpret_cast<uint4*>(&lds[0][swz(pix, c)]) = val;
    }

    const int oA = wv * 2;                              // this wave's row pair
#pragma unroll 1
    for (int l = 0; l < 4; l++) {
        const uint4* wl = reinterpret_cast<const uint4*>(wfrag + l * 9216);
        const u16* src = lds[l & 1];
        u16* dst = lds[(l & 1) ^ 1];
        f32x4 vacc = (f32x4)0.f;
        __syncthreads();                                // prev writes visible

        f32x4 accA[2][2]; f32x4 accB[2][2];             // [mhalf][ntile]
#pragma unroll
        for (int mh = 0; mh < 2; mh++)
#pragma unroll
            for (int nt = 0; nt < 2; nt++) { accA[mh][nt] = (f32x4)0.f; accB[mh][nt] = (f32x4)0.f; }

        bf16x8 Wc[3][2], Wp[3][2];                      // cur / prev dy row
#pragma unroll
        for (int k = 0; k < 4; k++) {
            if (k > 0) {                                // rotate (reg rename)
#pragma unroll
                for (int d = 0; d < 3; d++)
#pragma unroll
                    for (int mh = 0; mh < 2; mh++) Wp[d][mh] = Wc[d][mh];
            }
            if (k <= 2) {                               // load dy=k row
#pragma unroll
                for (int d = 0; d < 3; d++)
#pragma unroll
                    for (int mh = 0; mh < 2; mh++) {
                        frag_cast fc;
                        fc.u = wl[((k * 3 + d) * 2 + mh) * 64 + lane];
                        Wc[d][mh] = fc.f;
                    }
            }
            int ri = oA - 1 + k;                        // input row
            if (ri >= 0 && ri < 32) {
                bf16x8 bfr[2][3];                       // [ntile][dx]
#pragma unroll
                for (int nt = 0; nt < 2; nt++)
#pragma unroll
                    for (int d = 0; d < 3; d++) {
                        int xx = nt * 16 + px + d - 1;
                        bool oob = ((unsigned)xx >= 32u);
                        int xs = oob ? (nt * 16 + px) : xx;
                        const uint4* pr = oob ? &zslot
                            : reinterpret_cast<const uint4*>(&src[swz(ri * 32 + xs, kq)]);
                        frag_cast fc;
                        fc.u = *pr;
                        bfr[nt][d] = fc.f;
                    }
                if (k <= 2) {                           // row oA, ky = k
#pragma unroll
                    for (int mh = 0; mh < 2; mh++)
#pragma unroll
                        for (int nt = 0; nt < 2; nt++)
#pragma unroll
                            for (int d = 0; d < 3; d++)
                                accA[mh][nt] = __builtin_amdgcn_mfma_f32_16x16x32_bf16(
                                    Wc[d][mh], bfr[nt][d], accA[mh][nt], 0, 0, 0);
                }
                if (k >= 1) {                           // row oA+1, ky = k-1
#pragma unroll
                    for (int mh = 0; mh < 2; mh++)
#pragma unroll
                        for (int nt = 0; nt < 2; nt++)
#pragma unroll
                            for (int d = 0; d < 3; d++)
                                accB[mh][nt] = __builtin_amdgcn_mfma_f32_16x16x32_bf16(
                                    Wp[d][mh], bfr[nt][d], accB[mh][nt], 0, 0, 0);
                }
            }
        }
        // epilogue: D col=lane&15(px), row(ch)=(lane>>4)*4+r
#pragma unroll
        for (int mh = 0; mh < 2; mh++)
#pragma unroll
            for (int nt = 0; nt < 2; nt++) {
                int cch = mh * 2 + (kq >> 1);
                int sub = (kq & 1) * 4;
                f32x4 a = accA[mh][nt];
                vacc += a * a;
                ushort4 h = make_ushort4(bfc(a[0]), bfc(a[1]), bfc(a[2]), bfc(a[3]));
                int P0 = oA * 32 + nt * 16 + px;
                *reinterpret_cast<ushort4*>(&dst[swz(P0, cch) + sub]) = h;
                f32x4 c = accB[mh][nt];
                vacc += c * c;
                ushort4 h2 = make_ushort4(bfc(c[0]), bfc(c[1]), bfc(c[2]), bfc(c[3]));
                int P1 = (oA + 1) * 32 + nt * 16 + px;
                *reinterpret_cast<ushort4*>(&dst[swz(P1, cch) + sub]) = h2;
            }
        vn[l] = vacc[0] + vacc[1] + vacc[2] + vacc[3];
    }

    // ---- norm chain -> c4[b] ----
#pragma unroll
    for (int l = 0; l < 4; l++)
#pragma unroll
        for (int off = 32; off; off >>= 1) vn[l] += __shfl_xor(vn[l], off);
    if (lane == 0) {
#pragma unroll
        for (int l = 0; l < 4; l++) red[wv][l] = vn[l];
    }
    __syncthreads();                                    // red + final lds[0] visible
    float c = 1.f;
#pragma unroll
    for (int l = 0; l < 4; l++) {
        float n = 0.f;
#pragma unroll
        for (int w = 0; w < 16; w++) n += red[w][l];
        c = c * (2.f / (2.f + c * c * n));
    }
    if (tid == 0) c4[b] = c;

    // ---- writeback final activation (lds[0], unswizzle -> linear NHWC) ----
    u16* ub = u4 + (size_t)b * 32768;
#pragma unroll
    for (int it = 0; it < 4; it++) {
        int pix = it * 256 + wv * 16 + px;
        int cch = kq;
        *reinterpret_cast<uint4*>(ub + pix * 32 + cch * 8) =
            *reinterpret_cast<const uint4*>(&lds[0][swz(pix, cch)]);
    }
}

// --------------- FC: MFMA, M=16(j), N=16 samples, 32-way k-split ------------
// Wave-private LDS staging: 4-lane-contiguous 64B global loads (coalesced),
// swizzled LDS slots (2-way banks), T14 split (load chunk c+1 -> regs, compute
// chunk c, then write regs -> LDS). No barriers (slots are wave-private).
#define FSTG 4
__global__ void __launch_bounds__(256)
fc_mfma_k(const u16* __restrict__ u4, const u16* __restrict__ wfc,
          float* __restrict__ tmp)
{
    __shared__ uint4 sb[2][4 * FSTG * 64];              // 2 x 16KB
    const int lane = threadIdx.x & 63;
    const int wv = threadIdx.x >> 6;
    // XCD-grouped remap: the 8 blocks sharing one sample-tile -> same bid&7
    const int rb = ((blockIdx.x & 7) << 6) + (blockIdx.x >> 3);
    const int wid = rb * 4 + wv;                        // 0..2047
    const int kc = wid & 31;                            // k-chunk (1024 elems)
    const int st = wid >> 5;                            // sample tile (16)
    const int px = lane & 15, kq = lane >> 4;
    const int a = lane >> 2, p = lane & 3;              // staging: sample, piece
    const u16* gB = u4 + (size_t)(st * 16 + a) * 32768 + kc * 1024 + p * 8;
    const int wslot = wv * FSTG * 64 + a * 4 + (p ^ (a & 3));
    const int rslot = wv * FSTG * 64 + px * 4 + (kq ^ (px & 3));
    const uint4* Ah = reinterpret_cast<const uint4*>(wfc) + kc * 32 * 64 + lane;
    const uint4* Al = Ah + 65536;
    f32x4 acc = (f32x4)0.f;
    uint4 rg[FSTG];

#pragma unroll
    for (int si = 0; si < FSTG; si++)
        rg[si] = *reinterpret_cast<const uint4*>(gB + si * 32);
#pragma unroll
    for (int si = 0; si < FSTG; si++)
        sb[0][wslot + si * 64] = rg[si];

#pragma unroll 1
    for (int c2 = 0; c2 < 8; c2++) {
        if (c2 < 7) {
#pragma unroll
            for (int si = 0; si < FSTG; si++)
                rg[si] = *reinterpret_cast<const uint4*>(gB + ((c2 + 1) * FSTG + si) * 32);
        }
#pragma unroll
        for (int si = 0; si < FSTG; si++) {
            int s = c2 * FSTG + si;
            frag_cast aa, al2, bb;
            aa.u  = Ah[s * 64];
            al2.u = Al[s * 64];
            bb.u  = sb[c2 & 1][rslot + si * 64];
            acc = __builtin_amdgcn_mfma_f32_16x16x32_bf16(aa.f,  bb.f, acc, 0, 0, 0);
            acc = __builtin_amdgcn_mfma_f32_16x16x32_bf16(al2.f, bb.f, acc, 0, 0, 0);
        }
        if (c2 < 7) {
#pragma unroll
            for (int si = 0; si < FSTG; si++)
                sb[(c2 + 1) & 1][wslot + si * 64] = rg[si];
        }
    }
    int sample = st * 16 + px;                          // D col = lane&15
#pragma unroll
    for (int r = 0; r < 4; r++) {
        int j = kq * 4 + r;                             // D row
        if (j < 10) atomicAdd(&tmp[sample * 10 + j], acc[r]);
    }
}

// ------------------- finalize: out = c4[b]*tmp + bias -----------------------
__global__ void finalize_k(const float* __restrict__ tmp, const float* __restrict__ c4,
                           const float* __restrict__ fcb, float* __restrict__ out)
{
    int i = blockIdx.x * 256 + threadIdx.x;
    if (i >= 10240) return;
    int b = i / 10, j = i - b * 10;
    out[i] = c4[b] * tmp[i] + fcb[j];
}

// ------------------------------- launcher -----------------------------------
extern "C" void kernel_launch(void* const* d_in, const int* in_sizes, int n_in,
                              void* d_out, int out_size, void* d_ws, size_t ws_size,
                              hipStream_t stream)
{
    const float* x   = (const float*)d_in[0];
    const float* cw0 = (const float*)d_in[1];
    const float* cw1 = (const float*)d_in[2];
    const float* cw2 = (const float*)d_in[3];
    const float* cw3 = (const float*)d_in[4];
    const float* fcw = (const float*)d_in[5];
    const float* fcb = (const float*)d_in[6];
    float* out = (float*)d_out;
    char* ws = (char*)d_ws;

    // ws layout (~66.2 MB)
    const size_t USZ = (size_t)1024 * 32768 * 2;        // 64 MB activations
    u16* uA    = (u16*)ws;
    u16* wfrag = (u16*)(ws + USZ);                      // 73728 B (pad 81920)
    u16* wfc   = (u16*)(ws + USZ + 81920);              // 2 MB (hi+lo)
    float* tmp = (float*)(ws + USZ + 81920 + 2097152);  // 40960 B
    float* c4  = tmp + 10240;                           // 4096 B

    prep_all_k<<<275, 256, 0, stream>>>(cw0, cw1, cw2, cw3, fcw, wfrag, wfc, tmp);
    net_k<<<1024, 1024, 0, stream>>>(x, wfrag, uA, c4);
    fc_mfma_k<<<512, 256, 0, stream>>>(uA, wfc, tmp);
    finalize_k<<<40, 256, 0, stream>>>(tmp, c4, fcb, out);
}